// Round 19
// baseline (129.207 us; speedup 1.0000x reference)
//
#include <hip/hip_runtime.h>
#include <hip/hip_bf16.h>

typedef __bf16 bf16;
typedef __bf16 bf16x8 __attribute__((ext_vector_type(8)));
typedef __bf16 bf16x4 __attribute__((ext_vector_type(4)));
typedef float f32x4 __attribute__((ext_vector_type(4)));
typedef unsigned int u32;

static constexpr int S = 2048, U = 1024, NB = 2, NH = 16, HD = 64;
static constexpr float NEGC = -4294967295.0f;

__device__ __forceinline__ void gload_lds16(const void* g, void* l) {
  __builtin_amdgcn_global_load_lds((const __attribute__((address_space(1))) void*)g,
                                   (__attribute__((address_space(3))) void*)l, 16, 0, 0);
}

// ---------------- W fp32 -> bf16 (A conversion + masks now fused into proj) ----------------
__global__ __launch_bounds__(128) void conv_kernel(
    const float* __restrict__ Wq, const float* __restrict__ Wk, const float* __restrict__ Wv,
    bf16* __restrict__ Wb)
{
  const int idx = blockIdx.x;               // 0..3071
  const int tid = threadIdx.x;
  const int zz = idx >> 10, row = idx & 1023;
  const float* src = (zz == 0 ? Wq : (zz == 1 ? Wk : Wv)) + (size_t)row * U;
  bf16* dst = Wb + ((size_t)zz << 20) + (size_t)row * U;
  float4 f0 = *reinterpret_cast<const float4*>(src + tid * 8);
  float4 f1 = *reinterpret_cast<const float4*>(src + tid * 8 + 4);
  bf16x8 o;
  o[0]=(bf16)f0.x; o[1]=(bf16)f0.y; o[2]=(bf16)f0.z; o[3]=(bf16)f0.w;
  o[4]=(bf16)f1.x; o[5]=(bf16)f1.y; o[6]=(bf16)f1.z; o[7]=(bf16)f1.w;
  *reinterpret_cast<bf16x8*>(dst + tid * 8) = o;
}

// ---------------- QKV projection: fp32 A direct (fused conversion + masks) ----------------
// A staged from fp32 global via regs (coalesced: 16 threads/row x 4 floats = 16 lines/instr),
// converted to bf16, ds_written into the swizzled layout; W staged via global_load_lds as
// before. Double-buffered, one barrier/iter (writes go to buf^1 while reading buf).
// n==0 blocks also compute exact fp32 row sums -> qmask (z=0) / additive kmask (z=1).
__global__ __launch_bounds__(256) void proj_kernel(
    const float* __restrict__ q_in, const float* __restrict__ k_in, const float* __restrict__ v_in,
    const float* __restrict__ bq, const float* __restrict__ bk, const float* __restrict__ bv,
    const bf16* __restrict__ Wb, bf16* __restrict__ Qb, bf16* __restrict__ Kb, bf16* __restrict__ Vt,
    float* __restrict__ masks)
{
  const int z = blockIdx.z;
  const float* A    = z == 0 ? q_in : (z == 1 ? k_in : v_in);
  const float* bias = z == 0 ? bq : (z == 1 ? bk : bv);
  bf16* O           = z == 0 ? Qb : Kb;       // z==2 goes through the Vt path
  const float sc    = z == 0 ? 0.125f : 1.0f;
  const bf16* W = Wb + ((size_t)z << 20);

  const int m0 = blockIdx.x * 128;
  const int n0 = blockIdx.y * 64;
  const int tid = threadIdx.x;
  const int lane = tid & 63;
  const int w = tid >> 6;
  const int lg = lane >> 4, li = lane & 15;
  const int wr = w >> 1, wc = w & 1;    // wave tile: 64 rows x 32 cols

  __shared__ bf16 As[2][128 * 64];   // [buf][row][chunk*8] swizzled, 16 KB each
  __shared__ bf16 Ws[2][64 * 64];    // [buf][row][chunk*8] swizzled,  8 KB each

  f32x4 acc[4][2] = {};
  float4 a_pre[8];
  float rsum[8];
#pragma unroll
  for (int j = 0; j < 8; ++j) rsum[j] = 0.f;
  const bool doMask = (blockIdx.y == 0) && (z < 2);

  // A: issue 8 fp32 float4 loads for tile k0 (c = j*256+tid: row=c>>4, q4=c&15)
  auto issueA = [&](int k0) {
#pragma unroll
    for (int j = 0; j < 8; ++j) {
      int c = j * 256 + tid;
      int row = c >> 4, q4 = c & 15;
      a_pre[j] = *reinterpret_cast<const float4*>(A + (size_t)(m0 + row) * U + k0 + q4 * 4);
    }
  };
  // W: 2 DMA instr/wave, global pre-swizzled, linear LDS dest
  auto issueW = [&](int buf, int k0) {
#pragma unroll
    for (int j = 0; j < 2; ++j) {
      int c = j * 256 + tid;
      int row = c >> 3, g = c & 7;
      gload_lds16(W + (size_t)(n0 + row) * U + k0 + ((g ^ (row & 7)) << 3),
                  (char*)Ws[buf] + (size_t)c * 16);
    }
  };
  // convert a_pre -> bf16, write into swizzled As[buf]; accumulate row sums
  auto commitA = [&](int buf) {
#pragma unroll
    for (int j = 0; j < 8; ++j) {
      int c = j * 256 + tid;
      int row = c >> 4, q4 = c & 15;
      float4 f = a_pre[j];
      rsum[j] += f.x + f.y + f.z + f.w;
      bf16x4 o4;
      o4[0] = (bf16)f.x; o4[1] = (bf16)f.y; o4[2] = (bf16)f.z; o4[3] = (bf16)f.w;
      int ch = q4 >> 1, half = q4 & 1;
      *reinterpret_cast<bf16x4*>((char*)As[buf] + row * 128 + (((ch ^ (row & 7)) << 4) | (half << 3))) = o4;
    }
  };

  // prologue: tile 0
  issueA(0);
  issueW(0, 0);
  commitA(0);
  __syncthreads();

  int cur = 0;
  for (int kt = 0; kt < 16; ++kt) {
    if (kt < 15) {
      issueA((kt + 1) * 64);           // latency hides under MFMA phase
      issueW(cur ^ 1, (kt + 1) * 64);
    }

    const bf16* AsC = As[cur];
    const bf16* WsC = Ws[cur];
    __builtin_amdgcn_s_setprio(1);
#pragma unroll
    for (int s = 0; s < 2; ++s) {
      const int gf = s * 4 + lg;
      const int gx = (gf ^ (li & 7)) << 3;   // swizzled chunk byte offset (row&7 == li&7)
      bf16x8 af[4], wf[2];
#pragma unroll
      for (int mi = 0; mi < 4; ++mi)
        af[mi] = *reinterpret_cast<const bf16x8*>(AsC + (size_t)(wr * 64 + mi * 16 + li) * 64 + gx);
#pragma unroll
      for (int ni = 0; ni < 2; ++ni)
        wf[ni] = *reinterpret_cast<const bf16x8*>(WsC + (size_t)(wc * 32 + ni * 16 + li) * 64 + gx);
#pragma unroll
      for (int mi = 0; mi < 4; ++mi)
#pragma unroll
        for (int ni = 0; ni < 2; ++ni)
          acc[mi][ni] = __builtin_amdgcn_mfma_f32_16x16x32_bf16(af[mi], wf[ni], acc[mi][ni], 0, 0, 0);
    }
    __builtin_amdgcn_s_setprio(0);

    if (kt < 15) commitA(cur ^ 1);     // writes buf^1 while others may still read buf: safe
    __syncthreads();                   // ds_writes visible + W-DMA drained for next iter
    cur ^= 1;
  }

  // masks: exact fp32 row sums (full K covered by this block) -> write by n==0 blocks
  if (doMask) {
#pragma unroll
    for (int j = 0; j < 8; ++j) {
      float s = rsum[j];
      s += __shfl_xor(s, 1, 64);
      s += __shfl_xor(s, 2, 64);
      s += __shfl_xor(s, 4, 64);
      s += __shfl_xor(s, 8, 64);
      if ((tid & 15) == 0) {
        int row = (j * 256 + tid) >> 4;
        bool nz = (s != 0.0f);
        if (z == 0) masks[m0 + row] = nz ? 1.0f : 0.0f;           // qmask multiplicative
        else        masks[4096 + m0 + row] = nz ? 0.0f : NEGC;    // kmask additive
      }
    }
  }

  // epilogue: bias+relu+scale -> swizzled LDS scratch -> coalesced stores
  // swizzle: stored_col = col ^ ((row&7)<<3) ^ (((row>>3)&7)<<3)  (transpose-read <=2-way)
  bf16* scr = (bf16*)As;               // 128 x 64 bf16 = 16 KB
#pragma unroll
  for (int ni = 0; ni < 2; ++ni) {
    int col = wc * 32 + ni * 16 + li;
    float bv_ = bias[n0 + col];
#pragma unroll
    for (int mi = 0; mi < 4; ++mi) {
#pragma unroll
      for (int r = 0; r < 4; ++r) {
        int row = wr * 64 + mi * 16 + lg * 4 + r;
        float v = acc[mi][ni][r] + bv_;
        v = (v > 0.f ? v : 0.f) * sc;
        scr[row * 64 + (col ^ ((row & 7) << 3) ^ (((row >> 3) & 7) << 3))] = (bf16)v;
      }
    }
  }
  __syncthreads();
  if (z != 2) {
    // row-major coalesced 16B stores to Q/K
    const int rbase = w * 32 + (lane >> 3);
    const int i = lane & 7;
#pragma unroll
    for (int p = 0; p < 4; ++p) {
      int rr = rbase + p * 8;
      bf16x8 v = *reinterpret_cast<const bf16x8*>(
          scr + rr * 64 + ((i ^ (rr & 7) ^ ((rr >> 3) & 7)) << 3));
      *reinterpret_cast<bf16x8*>(O + (size_t)(m0 + rr) * U + n0 + i * 8) = v;
    }
  } else {
    // fused V transpose: store Vt[hb][d][s] directly
    const int b2 = m0 >> 11;           // batch
    const int s0 = m0 & 2047;          // seq offset
    const int hb2 = blockIdx.y * 2 + b2;
    const int sc2 = tid & 15;          // s-chunk (8 s each)
#pragma unroll
    for (int p = 0; p < 4; ++p) {
      int d = p * 16 + (tid >> 4);
      bf16x8 v;
#pragma unroll
      for (int i = 0; i < 8; ++i)
        v[i] = scr[(sc2 * 8 + i) * 64 + (d ^ (i << 3) ^ ((sc2 & 7) << 3))];
      *reinterpret_cast<bf16x8*>(Vt + (size_t)(hb2 * 64 + d) * S + s0 + sc2 * 8) = v;
    }
  }
}

// ---------------- causal flash attention: swapped QK^T, in-lane softmax + defer-max (exact R17) ----------------
__global__ __launch_bounds__(512) void flash_kernel(
    const bf16* __restrict__ Qb, const bf16* __restrict__ Kb, const bf16* __restrict__ Vt,
    const float* __restrict__ masks, float* __restrict__ Out)
{
  const int bid = blockIdx.x;          // grid 512
  const int hb = bid & 31;
  const int t = bid >> 5;              // 0..15
  const int qt2 = (t < 8) ? t : 23 - t;
  const int h = hb >> 1, b = hb & 1;
  const int q0 = qt2 * 128;
  const int nIter = 2 * qt2 + 2;
  const int tid = threadIdx.x;
  const int lane = tid & 63, w = tid >> 6;   // w 0..7
  const int lg = lane >> 4, li = lane & 15;
  const float* qmask = masks;
  const float* kmask = masks + 4096;   // additive: 0 or NEGC

  __shared__ bf16 Ks[2][8 * 64 * 8];   // [buf][g=d/8][k=64][8], 8 KB each
  __shared__ bf16 Vs[2][8 * 64 * 8];   // [buf][g2=k/8][d=64][8], 8 KB each
  __shared__ float Ms[2][64];          // [buf][k] additive key mask strip

  const int qq = q0 + w * 16 + li;     // this lane's q-row
  const bf16* qptr = Qb + (size_t)(b * S + qq) * U + h * 64;
  bf16x8 qf0 = *reinterpret_cast<const bf16x8*>(qptr + lg * 8);
  bf16x8 qf1 = *reinterpret_cast<const bf16x8*>(qptr + 32 + lg * 8);

  f32x4 oaccT[4] = {};                 // O^T frag: lane holds d = c2*16+lg*4+r for its q
  float m_run = -3.0e38f;
  float l_part = 0.0f;                 // per-lane PARTIAL row sum (combined once at end)

  const size_t krow_base = (size_t)b * S;
  const size_t vrow_base = (size_t)hb * 64;
  const int gK = tid >> 6, rK = tid & 63;

  auto stage = [&](int buf, int k0) {
    gload_lds16(Kb + (krow_base + k0 + rK) * U + h * 64 + gK * 8, (char*)Ks[buf] + (size_t)tid * 16);
    gload_lds16(Vt + (vrow_base + rK) * S + k0 + gK * 8,          (char*)Vs[buf] + (size_t)tid * 16);
  };

  // prologue: tile 0
  stage(0, 0);
  if (tid < 64) Ms[0][tid] = kmask[b * S + tid];
  __syncthreads();

  int cur = 0;
  for (int kv = 0; kv < nIter; ++kv) {
    const int k0 = kv * 64;
    float kaddn = 0.f;
    if (kv + 1 < nIter) {
      stage(cur ^ 1, k0 + 64);                         // prefetch hides under compute
      if (tid < 64) kaddn = kmask[b * S + k0 + 64 + tid];
    }

    const bf16* KsC = Ks[cur];
    const bf16* VsC = Vs[cur];

    // QK^T swapped: st[c] = S^T fragment
    f32x4 st[4] = {};
    __builtin_amdgcn_s_setprio(1);
#pragma unroll
    for (int s = 0; s < 2; ++s) {
      bf16x8 qf = s ? qf1 : qf0;
#pragma unroll
      for (int c = 0; c < 4; ++c) {
        bf16x8 kf = *reinterpret_cast<const bf16x8*>(KsC + (size_t)((s * 4 + lg) * 64 + c * 16 + li) * 8);
        st[c] = __builtin_amdgcn_mfma_f32_16x16x32_bf16(kf, qf, st[c], 0, 0, 0);
      }
    }
    __builtin_amdgcn_s_setprio(0);

    // masks: additive key mask (LDS strip, broadcast reads); causal only on last 2 tiles
    float p[4][4];
#pragma unroll
    for (int c = 0; c < 4; ++c) {
      f32x4 ka = *reinterpret_cast<const f32x4*>(&Ms[cur][c * 16 + lg * 4]);
#pragma unroll
      for (int r = 0; r < 4; ++r) p[c][r] = st[c][r] + ka[r];
    }
    if (kv >= 2 * qt2) {
#pragma unroll
      for (int c = 0; c < 4; ++c)
#pragma unroll
        for (int r = 0; r < 4; ++r)
          if (k0 + c * 16 + lg * 4 + r > qq) p[c][r] = NEGC;
    }

    // defer-max (T13): per-lane 16-value max; wave-uniform vote skips the
    // max-shuffles + m/alpha update + oacc rescale in the common case.
    float mx = p[0][0];
#pragma unroll
    for (int c = 0; c < 4; ++c)
#pragma unroll
      for (int r = 0; r < 4; ++r) mx = fmaxf(mx, p[c][r]);
    if (!__all(mx <= m_run + 8.0f)) {
      mx = fmaxf(mx, __shfl_xor(mx, 16, 64));
      mx = fmaxf(mx, __shfl_xor(mx, 32, 64));
      float mn = fmaxf(m_run, mx);
      float alpha = __expf(m_run - mn);
      m_run = mn;
      l_part *= alpha;
#pragma unroll
      for (int c2 = 0; c2 < 4; ++c2)
#pragma unroll
        for (int r = 0; r < 4; ++r) oaccT[c2][r] *= alpha;
    }
    float ps = 0.f;
#pragma unroll
    for (int c = 0; c < 4; ++c)
#pragma unroll
      for (int r = 0; r < 4; ++r) {
        float pv = __expf(p[c][r] - m_run);   // bounded by e^8 on skip iters
        p[c][r] = pv;
        ps += pv;
      }
    l_part += ps;

    // pack P to bf16 pairs (u32) for register exchange
    u32 pk[4][2];
#pragma unroll
    for (int c = 0; c < 4; ++c) {
      union { bf16 hh[2]; u32 ww; } u0, u1;
      u0.hh[0] = (bf16)p[c][0]; u0.hh[1] = (bf16)p[c][1];
      u1.hh[0] = (bf16)p[c][2]; u1.hh[1] = (bf16)p[c][3];
      pk[c][0] = u0.ww; pk[c][1] = u1.ww;
    }

    // PV: O^T += V^T_frag x P^T_frag with permuted k-blocks.
    const bool lgEven = (lg & 1) == 0;
    __builtin_amdgcn_s_setprio(1);
#pragma unroll
    for (int s2 = 0; s2 < 2; ++s2) {
      u32 o0 = lgEven ? pk[(s2 << 1)][0]     : pk[(s2 << 1) | 1][0];
      u32 o1 = lgEven ? pk[(s2 << 1)][1]     : pk[(s2 << 1) | 1][1];
      u32 s0 = lgEven ? pk[(s2 << 1) | 1][0] : pk[(s2 << 1)][0];
      u32 s1 = lgEven ? pk[(s2 << 1) | 1][1] : pk[(s2 << 1)][1];
      u32 r0 = (u32)__shfl_xor((int)s0, 16, 64);
      u32 r1 = (u32)__shfl_xor((int)s1, 16, 64);
      union { u32 ww[4]; bf16x8 vv; } pt;
      pt.ww[0] = lgEven ? o0 : r0;
      pt.ww[1] = lgEven ? o1 : r1;
      pt.ww[2] = lgEven ? r0 : o0;
      pt.ww[3] = lgEven ? r1 : o1;
      const int g2v = s2 * 4 + (((lg & 1) << 1) | (lg >> 1));
#pragma unroll
      for (int c2 = 0; c2 < 4; ++c2) {
        bf16x8 vf = *reinterpret_cast<const bf16x8*>(VsC + (size_t)(g2v * 64 + c2 * 16 + li) * 8);
        oaccT[c2] = __builtin_amdgcn_mfma_f32_16x16x32_bf16(vf, pt.vv, oaccT[c2], 0, 0, 0);
      }
    }
    __builtin_amdgcn_s_setprio(0);

    if (kv + 1 < nIter && tid < 64) Ms[cur ^ 1][tid] = kaddn;
    __syncthreads();   // next-tile DMA complete + all reads of cur done
    cur ^= 1;
  }

  // epilogue: combine partial l across the 4 owning lanes (deferred from per-iter),
  // normalize, query-mask, scattered O^T store (L2 write-back merges)
  float l_run = l_part;
  l_run += __shfl_xor(l_run, 16, 64);
  l_run += __shfl_xor(l_run, 32, 64);
  float qm = qmask[b * S + qq];
  float sc = qm / l_run;
  float* orow = Out + (size_t)(b * S + qq) * U + h * 64;
#pragma unroll
  for (int c2 = 0; c2 < 4; ++c2)
#pragma unroll
    for (int r = 0; r < 4; ++r)
      orow[c2 * 16 + lg * 4 + r] = oaccT[c2][r] * sc;
}

// ---------------- residual + LayerNorm (ddof=1), in-place on d_out, float4 ----------------
__global__ __launch_bounds__(256) void ln_kernel(float* __restrict__ out, const float* __restrict__ queries,
                                                 const float* __restrict__ gamma, const float* __restrict__ beta)
{
  int row = blockIdx.x;
  const float4* q4 = reinterpret_cast<const float4*>(queries + (size_t)row * U);
  float4* o4 = reinterpret_cast<float4*>(out + (size_t)row * U);
  int tid = threadIdx.x;
  float4 ov = o4[tid], qv = q4[tid];
  float4 x;
  x.x = ov.x + qv.x; x.y = ov.y + qv.y; x.z = ov.z + qv.z; x.w = ov.w + qv.w;
  float s  = x.x + x.y + x.z + x.w;
  float s2 = x.x * x.x + x.y * x.y + x.z * x.z + x.w * x.w;
#pragma unroll
  for (int off = 1; off < 64; off <<= 1) { s += __shfl_xor(s, off, 64); s2 += __shfl_xor(s2, off, 64); }
  __shared__ float ss[4], ssq[4];
  int w = tid >> 6;
  if ((tid & 63) == 0) { ss[w] = s; ssq[w] = s2; }
  __syncthreads();
  s = ss[0] + ss[1] + ss[2] + ss[3];
  s2 = ssq[0] + ssq[1] + ssq[2] + ssq[3];
  float mean = s * (1.0f / 1024.0f);
  float var = (s2 - 1024.0f * mean * mean) * (1.0f / 1023.0f);
  var = fmaxf(var, 0.f);
  float inv = 1.0f / (sqrtf(var) + 1e-8f);
  float4 g4 = reinterpret_cast<const float4*>(gamma)[tid];
  float4 b4 = reinterpret_cast<const float4*>(beta)[tid];
  float4 r;
  r.x = g4.x * (x.x - mean) * inv + b4.x;
  r.y = g4.y * (x.y - mean) * inv + b4.y;
  r.z = g4.z * (x.z - mean) * inv + b4.z;
  r.w = g4.w * (x.w - mean) * inv + b4.w;
  o4[tid] = r;
}

extern "C" void kernel_launch(void* const* d_in, const int* in_sizes, int n_in,
                              void* d_out, int out_size, void* d_ws, size_t ws_size,
                              hipStream_t stream) {
  const float* queries = (const float*)d_in[0];
  const float* keys    = (const float*)d_in[1];
  const float* values  = (const float*)d_in[2];
  const float* Wq = (const float*)d_in[3];
  const float* bq = (const float*)d_in[4];
  const float* Wk = (const float*)d_in[5];
  const float* bk = (const float*)d_in[6];
  const float* Wv = (const float*)d_in[7];
  const float* bv = (const float*)d_in[8];
  const float* gamma = (const float*)d_in[9];
  const float* beta  = (const float*)d_in[10];
  float* out = (float*)d_out;

  char* ws = (char*)d_ws;
  const size_t SZ = (size_t)4096 * 1024 * 2;           // one bf16 [4096][1024] tensor (8 MB)
  bf16* Qb = (bf16*)(ws);
  bf16* Kb = (bf16*)(ws + SZ);
  bf16* Vt = (bf16*)(ws + 2 * SZ);                     // written directly by proj z==2
  bf16* Wb = (bf16*)(ws + 3 * SZ);                     // 3 x [1024][1024] bf16 (6 MB)
  float* masks = (float*)(ws + 3 * SZ + 3 * 2097152);  // qmask[4096], kmaskAdd[4096] (written by proj)

  conv_kernel<<<3072, 128, 0, stream>>>(Wq, Wk, Wv, Wb);
  proj_kernel<<<dim3(32, 16, 3), 256, 0, stream>>>(queries, keys, values, bq, bk, bv, Wb, Qb, Kb, Vt, masks);
  flash_kernel<<<512, 512, 0, stream>>>(Qb, Kb, Vt, masks, out);
  ln_kernel<<<4096, 256, 0, stream>>>(out, queries, gamma, beta);
}

// Round 20
// 112.686 us; speedup vs baseline: 1.1466x; 1.1466x over previous
//
#include <hip/hip_runtime.h>
#include <hip/hip_bf16.h>

typedef __bf16 bf16;
typedef __bf16 bf16x8 __attribute__((ext_vector_type(8)));
typedef __bf16 bf16x4 __attribute__((ext_vector_type(4)));
typedef float f32x4 __attribute__((ext_vector_type(4)));
typedef unsigned int u32;

static constexpr int S = 2048, U = 1024, NB = 2, NH = 16, HD = 64;
static constexpr float NEGC = -4294967295.0f;
static constexpr float LOG2E = 1.44269504088896f;

__device__ __forceinline__ void gload_lds16(const void* g, void* l) {
  __builtin_amdgcn_global_load_lds((const __attribute__((address_space(1))) void*)g,
                                   (__attribute__((address_space(3))) void*)l, 16, 0, 0);
}

// ---------------- fused fp32->bf16 conversion (A + W) + padding masks ----------------
// masks[0..4095] = qmask (0/1); masks[4096..8191] = key additive mask (0 or NEGC)
__global__ __launch_bounds__(128) void conv_kernel(
    const float* __restrict__ queries, const float* __restrict__ keys, const float* __restrict__ values,
    const float* __restrict__ Wq, const float* __restrict__ Wk, const float* __restrict__ Wv,
    bf16* __restrict__ Aq, bf16* __restrict__ Ak, bf16* __restrict__ Av,
    bf16* __restrict__ Wb, float* __restrict__ masks)
{
  const int idx = blockIdx.x;               // 0..15359
  const int tid = threadIdx.x;
  const float* src;
  bf16* dst;
  if (idx < 4096)       { src = queries + (size_t)idx * U;          dst = Aq + (size_t)idx * U; }
  else if (idx < 8192)  { src = keys + (size_t)(idx - 4096) * U;    dst = Ak + (size_t)(idx - 4096) * U; }
  else if (idx < 12288) { src = values + (size_t)(idx - 8192) * U;  dst = Av + (size_t)(idx - 8192) * U; }
  else {
    int r2 = idx - 12288;
    int zz = r2 >> 10, row = r2 & 1023;
    src = (zz == 0 ? Wq : (zz == 1 ? Wk : Wv)) + (size_t)row * U;
    dst = Wb + ((size_t)zz << 20) + (size_t)row * U;
  }
  float4 f0 = *reinterpret_cast<const float4*>(src + tid * 8);
  float4 f1 = *reinterpret_cast<const float4*>(src + tid * 8 + 4);
  bf16x8 o;
  o[0]=(bf16)f0.x; o[1]=(bf16)f0.y; o[2]=(bf16)f0.z; o[3]=(bf16)f0.w;
  o[4]=(bf16)f1.x; o[5]=(bf16)f1.y; o[6]=(bf16)f1.z; o[7]=(bf16)f1.w;
  *reinterpret_cast<bf16x8*>(dst + tid * 8) = o;

  if (idx < 8192) {   // padding masks from row sums
    float s = f0.x + f0.y + f0.z + f0.w + f1.x + f1.y + f1.z + f1.w;
#pragma unroll
    for (int off = 1; off < 64; off <<= 1) s += __shfl_xor(s, off, 64);
    __shared__ float ss[2];
    if ((tid & 63) == 0) ss[tid >> 6] = s;
    __syncthreads();
    if (tid == 0) {
      bool nz = (ss[0] + ss[1]) != 0.0f;
      masks[idx] = (idx < 4096) ? (nz ? 1.0f : 0.0f)     // qmask multiplicative
                                : (nz ? 0.0f : NEGC);    // kmask additive
    }
  }
}

// ---------------- QKV projection (coalesced staging; z==2 writes Vt transposed) ----------------
// Q gets sc = 0.125*log2e: flash's softmax then uses exp2 directly (saves a v_mul per exp).
__global__ __launch_bounds__(256) void proj_kernel(
    const bf16* __restrict__ Aq, const bf16* __restrict__ Ak, const bf16* __restrict__ Av,
    const float* __restrict__ bq, const float* __restrict__ bk, const float* __restrict__ bv,
    const bf16* __restrict__ Wb, bf16* __restrict__ Qb, bf16* __restrict__ Kb, bf16* __restrict__ Vt)
{
  const int z = blockIdx.z;
  const bf16* A     = z == 0 ? Aq : (z == 1 ? Ak : Av);
  const float* bias = z == 0 ? bq : (z == 1 ? bk : bv);
  bf16* O           = z == 0 ? Qb : Kb;       // z==2 goes through the Vt path
  const float sc    = z == 0 ? 0.125f * LOG2E : 1.0f;
  const bf16* W = Wb + ((size_t)z << 20);

  const int m0 = blockIdx.x * 128;
  const int n0 = blockIdx.y * 64;
  const int tid = threadIdx.x;
  const int lane = tid & 63;
  const int w = tid >> 6;
  const int lg = lane >> 4, li = lane & 15;
  const int wr = w >> 1, wc = w & 1;    // wave tile: 64 rows x 32 cols

  __shared__ bf16 As[2][128 * 64];   // [buf][row][chunk*8], 16 KB each
  __shared__ bf16 Ws[2][64 * 64];    // [buf][row][chunk*8],  8 KB each

  f32x4 acc[4][2] = {};

  auto stage = [&](int buf, int k0) {
#pragma unroll
    for (int j = 0; j < 4; ++j) {      // A: 4 VMEM instr/wave, 16 lines each
      int c = j * 256 + tid;
      int row = c >> 3, g = c & 7;
      gload_lds16(A + (size_t)(m0 + row) * U + k0 + ((g ^ (row & 7)) << 3),
                  (char*)As[buf] + (size_t)c * 16);
    }
#pragma unroll
    for (int j = 0; j < 2; ++j) {      // W: 2 VMEM instr/wave
      int c = j * 256 + tid;
      int row = c >> 3, g = c & 7;
      gload_lds16(W + (size_t)(n0 + row) * U + k0 + ((g ^ (row & 7)) << 3),
                  (char*)Ws[buf] + (size_t)c * 16);
    }
  };

  stage(0, 0);                         // 6 outstanding

  int cur = 0;
  for (int kt = 0; kt < 16; ++kt) {
    if (kt < 15) {
      stage(cur ^ 1, (kt + 1) * 64);   // +6 -> 12 outstanding
      asm volatile("s_waitcnt vmcnt(6)" ::: "memory");   // tile kt landed; next 6 stay in flight
    } else {
      asm volatile("s_waitcnt vmcnt(0)" ::: "memory");
    }
    __builtin_amdgcn_s_barrier();      // all waves' tile-kt DMA complete
    __builtin_amdgcn_sched_barrier(0); // no hoisting of ds_reads above the wait

    const bf16* AsC = As[cur];
    const bf16* WsC = Ws[cur];
    __builtin_amdgcn_s_setprio(1);
#pragma unroll
    for (int s = 0; s < 2; ++s) {
      const int gf = s * 4 + lg;
      const int gx = (gf ^ (li & 7)) << 3;   // swizzled chunk byte offset (row&7 == li&7)
      bf16x8 af[4], wf[2];
#pragma unroll
      for (int mi = 0; mi < 4; ++mi)
        af[mi] = *reinterpret_cast<const bf16x8*>(AsC + (size_t)(wr * 64 + mi * 16 + li) * 64 + gx);
#pragma unroll
      for (int ni = 0; ni < 2; ++ni)
        wf[ni] = *reinterpret_cast<const bf16x8*>(WsC + (size_t)(wc * 32 + ni * 16 + li) * 64 + gx);
#pragma unroll
      for (int mi = 0; mi < 4; ++mi)
#pragma unroll
        for (int ni = 0; ni < 2; ++ni)
          acc[mi][ni] = __builtin_amdgcn_mfma_f32_16x16x32_bf16(af[mi], wf[ni], acc[mi][ni], 0, 0, 0);
    }
    __builtin_amdgcn_s_setprio(0);
    __builtin_amdgcn_sched_barrier(0); // keep MFMA phase (and its ds_reads) before the barrier
    __builtin_amdgcn_s_barrier();      // all reads of cur done -> next iter may overwrite cur
    cur ^= 1;
  }

  // epilogue: bias+relu+scale -> swizzled LDS scratch -> coalesced stores
  // swizzle: stored_col = col ^ ((row&7)<<3) ^ (((row>>3)&7)<<3)  (transpose-read <=2-way)
  bf16* scr = (bf16*)As;               // 128 x 64 bf16 = 16 KB
#pragma unroll
  for (int ni = 0; ni < 2; ++ni) {
    int col = wc * 32 + ni * 16 + li;
    float bv_ = bias[n0 + col];
#pragma unroll
    for (int mi = 0; mi < 4; ++mi) {
#pragma unroll
      for (int r = 0; r < 4; ++r) {
        int row = wr * 64 + mi * 16 + lg * 4 + r;
        float v = acc[mi][ni][r] + bv_;
        v = (v > 0.f ? v : 0.f) * sc;
        scr[row * 64 + (col ^ ((row & 7) << 3) ^ (((row >> 3) & 7) << 3))] = (bf16)v;
      }
    }
  }
  __syncthreads();
  if (z != 2) {
    // row-major coalesced 16B stores to Q/K
    const int rbase = w * 32 + (lane >> 3);
    const int i = lane & 7;
#pragma unroll
    for (int p = 0; p < 4; ++p) {
      int rr = rbase + p * 8;
      bf16x8 v = *reinterpret_cast<const bf16x8*>(
          scr + rr * 64 + ((i ^ (rr & 7) ^ ((rr >> 3) & 7)) << 3));
      *reinterpret_cast<bf16x8*>(O + (size_t)(m0 + rr) * U + n0 + i * 8) = v;
    }
  } else {
    // fused V transpose: store Vt[hb][d][s] directly
    const int b2 = m0 >> 11;           // batch
    const int s0 = m0 & 2047;          // seq offset
    const int hb2 = blockIdx.y * 2 + b2;
    const int sc2 = tid & 15;          // s-chunk (8 s each)
#pragma unroll
    for (int p = 0; p < 4; ++p) {
      int d = p * 16 + (tid >> 4);
      bf16x8 v;
#pragma unroll
      for (int i = 0; i < 8; ++i)
        v[i] = scr[(sc2 * 8 + i) * 64 + (d ^ (i << 3) ^ ((sc2 & 7) << 3))];
      *reinterpret_cast<bf16x8*>(Vt + (size_t)(hb2 * 64 + d) * S + s0 + sc2 * 8) = v;
    }
  }
}

// ---------------- causal flash attention: swapped QK^T, in-lane softmax + defer-max, exp2 ----------------
__global__ __launch_bounds__(512) void flash_kernel(
    const bf16* __restrict__ Qb, const bf16* __restrict__ Kb, const bf16* __restrict__ Vt,
    const float* __restrict__ masks, float* __restrict__ Out)
{
  const int bid = blockIdx.x;          // grid 512
  const int hb = bid & 31;
  const int t = bid >> 5;              // 0..15
  const int qt2 = (t < 8) ? t : 23 - t;
  const int h = hb >> 1, b = hb & 1;
  const int q0 = qt2 * 128;
  const int nIter = 2 * qt2 + 2;
  const int tid = threadIdx.x;
  const int lane = tid & 63, w = tid >> 6;   // w 0..7
  const int lg = lane >> 4, li = lane & 15;
  const float* qmask = masks;
  const float* kmask = masks + 4096;   // additive: 0 or NEGC

  __shared__ bf16 Ks[2][8 * 64 * 8];   // [buf][g=d/8][k=64][8], 8 KB each
  __shared__ bf16 Vs[2][8 * 64 * 8];   // [buf][g2=k/8][d=64][8], 8 KB each
  __shared__ float Ms[2][64];          // [buf][k] additive key mask strip

  const int qq = q0 + w * 16 + li;     // this lane's q-row
  const bf16* qptr = Qb + (size_t)(b * S + qq) * U + h * 64;
  bf16x8 qf0 = *reinterpret_cast<const bf16x8*>(qptr + lg * 8);
  bf16x8 qf1 = *reinterpret_cast<const bf16x8*>(qptr + 32 + lg * 8);

  f32x4 oaccT[4] = {};                 // O^T frag: lane holds d = c2*16+lg*4+r for its q
  float m_run = -3.0e38f;
  float l_part = 0.0f;                 // per-lane PARTIAL row sum (combined once at end)

  const size_t krow_base = (size_t)b * S;
  const size_t vrow_base = (size_t)hb * 64;
  const int gK = tid >> 6, rK = tid & 63;

  auto stage = [&](int buf, int k0) {
    gload_lds16(Kb + (krow_base + k0 + rK) * U + h * 64 + gK * 8, (char*)Ks[buf] + (size_t)tid * 16);
    gload_lds16(Vt + (vrow_base + rK) * S + k0 + gK * 8,          (char*)Vs[buf] + (size_t)tid * 16);
  };

  // prologue: tile 0
  stage(0, 0);
  if (tid < 64) Ms[0][tid] = kmask[b * S + tid];
  __syncthreads();

  int cur = 0;
  for (int kv = 0; kv < nIter; ++kv) {
    const int k0 = kv * 64;
    float kaddn = 0.f;
    if (kv + 1 < nIter) {
      stage(cur ^ 1, k0 + 64);                         // prefetch hides under compute
      if (tid < 64) kaddn = kmask[b * S + k0 + 64 + tid];
    }

    const bf16* KsC = Ks[cur];
    const bf16* VsC = Vs[cur];

    // QK^T swapped: st[c] = S^T fragment (already in log2 scale: Q carries 0.125*log2e)
    f32x4 st[4] = {};
    __builtin_amdgcn_s_setprio(1);
#pragma unroll
    for (int s = 0; s < 2; ++s) {
      bf16x8 qf = s ? qf1 : qf0;
#pragma unroll
      for (int c = 0; c < 4; ++c) {
        bf16x8 kf = *reinterpret_cast<const bf16x8*>(KsC + (size_t)((s * 4 + lg) * 64 + c * 16 + li) * 8);
        st[c] = __builtin_amdgcn_mfma_f32_16x16x32_bf16(kf, qf, st[c], 0, 0, 0);
      }
    }
    __builtin_amdgcn_s_setprio(0);

    // masks: additive key mask (LDS strip, broadcast reads); causal only on last 2 tiles
    float p[4][4];
#pragma unroll
    for (int c = 0; c < 4; ++c) {
      f32x4 ka = *reinterpret_cast<const f32x4*>(&Ms[cur][c * 16 + lg * 4]);
#pragma unroll
      for (int r = 0; r < 4; ++r) p[c][r] = st[c][r] + ka[r];
    }
    if (kv >= 2 * qt2) {
#pragma unroll
      for (int c = 0; c < 4; ++c)
#pragma unroll
        for (int r = 0; r < 4; ++r)
          if (k0 + c * 16 + lg * 4 + r > qq) p[c][r] = NEGC;
    }

    // defer-max (T13): per-lane 16-value max; wave-uniform vote skips the
    // max-shuffles + m/alpha update + oacc rescale in the common case.
    // Threshold 8*log2e (we are in log2 units).
    float mx = p[0][0];
#pragma unroll
    for (int c = 0; c < 4; ++c)
#pragma unroll
      for (int r = 0; r < 4; ++r) mx = fmaxf(mx, p[c][r]);
    if (!__all(mx <= m_run + 11.5416f)) {
      mx = fmaxf(mx, __shfl_xor(mx, 16, 64));
      mx = fmaxf(mx, __shfl_xor(mx, 32, 64));
      float mn = fmaxf(m_run, mx);
      float alpha = exp2f(m_run - mn);
      m_run = mn;
      l_part *= alpha;
#pragma unroll
      for (int c2 = 0; c2 < 4; ++c2)
#pragma unroll
        for (int r = 0; r < 4; ++r) oaccT[c2][r] *= alpha;
    }
    float ps = 0.f;
#pragma unroll
    for (int c = 0; c < 4; ++c)
#pragma unroll
      for (int r = 0; r < 4; ++r) {
        float pv = exp2f(p[c][r] - m_run);   // bounded by 2^11.54 = e^8 on skip iters
        p[c][r] = pv;
        ps += pv;
      }
    l_part += ps;

    // pack P to bf16 pairs (u32) for register exchange
    u32 pk[4][2];
#pragma unroll
    for (int c = 0; c < 4; ++c) {
      union { bf16 hh[2]; u32 ww; } u0, u1;
      u0.hh[0] = (bf16)p[c][0]; u0.hh[1] = (bf16)p[c][1];
      u1.hh[0] = (bf16)p[c][2]; u1.hh[1] = (bf16)p[c][3];
      pk[c][0] = u0.ww; pk[c][1] = u1.ww;
    }

    // PV: O^T += V^T_frag x P^T_frag with permuted k-blocks.
    const bool lgEven = (lg & 1) == 0;
    __builtin_amdgcn_s_setprio(1);
#pragma unroll
    for (int s2 = 0; s2 < 2; ++s2) {
      u32 o0 = lgEven ? pk[(s2 << 1)][0]     : pk[(s2 << 1) | 1][0];
      u32 o1 = lgEven ? pk[(s2 << 1)][1]     : pk[(s2 << 1) | 1][1];
      u32 s0 = lgEven ? pk[(s2 << 1) | 1][0] : pk[(s2 << 1)][0];
      u32 s1 = lgEven ? pk[(s2 << 1) | 1][1] : pk[(s2 << 1)][1];
      u32 r0 = (u32)__shfl_xor((int)s0, 16, 64);
      u32 r1 = (u32)__shfl_xor((int)s1, 16, 64);
      union { u32 ww[4]; bf16x8 vv; } pt;
      pt.ww[0] = lgEven ? o0 : r0;
      pt.ww[1] = lgEven ? o1 : r1;
      pt.ww[2] = lgEven ? r0 : o0;
      pt.ww[3] = lgEven ? r1 : o1;
      const int g2v = s2 * 4 + (((lg & 1) << 1) | (lg >> 1));
#pragma unroll
      for (int c2 = 0; c2 < 4; ++c2) {
        bf16x8 vf = *reinterpret_cast<const bf16x8*>(VsC + (size_t)(g2v * 64 + c2 * 16 + li) * 8);
        oaccT[c2] = __builtin_amdgcn_mfma_f32_16x16x32_bf16(vf, pt.vv, oaccT[c2], 0, 0, 0);
      }
    }
    __builtin_amdgcn_s_setprio(0);

    if (kv + 1 < nIter && tid < 64) Ms[cur ^ 1][tid] = kaddn;
    __syncthreads();   // next-tile DMA complete + all reads of cur done
    cur ^= 1;
  }

  // epilogue: combine partial l across the 4 owning lanes (deferred from per-iter),
  // normalize, query-mask, scattered O^T store (L2 write-back merges)
  float l_run = l_part;
  l_run += __shfl_xor(l_run, 16, 64);
  l_run += __shfl_xor(l_run, 32, 64);
  float qm = qmask[b * S + qq];
  float sc = qm / l_run;
  float* orow = Out + (size_t)(b * S + qq) * U + h * 64;
#pragma unroll
  for (int c2 = 0; c2 < 4; ++c2)
#pragma unroll
    for (int r = 0; r < 4; ++r)
      orow[c2 * 16 + lg * 4 + r] = oaccT[c2][r] * sc;
}

// ---------------- residual + LayerNorm (ddof=1), in-place on d_out, float4 ----------------
__global__ __launch_bounds__(256) void ln_kernel(float* __restrict__ out, const float* __restrict__ queries,
                                                 const float* __restrict__ gamma, const float* __restrict__ beta)
{
  int row = blockIdx.x;
  const float4* q4 = reinterpret_cast<const float4*>(queries + (size_t)row * U);
  float4* o4 = reinterpret_cast<float4*>(out + (size_t)row * U);
  int tid = threadIdx.x;
  float4 ov = o4[tid], qv = q4[tid];
  float4 x;
  x.x = ov.x + qv.x; x.y = ov.y + qv.y; x.z = ov.z + qv.z; x.w = ov.w + qv.w;
  float s  = x.x + x.y + x.z + x.w;
  float s2 = x.x * x.x + x.y * x.y + x.z * x.z + x.w * x.w;
#pragma unroll
  for (int off = 1; off < 64; off <<= 1) { s += __shfl_xor(s, off, 64); s2 += __shfl_xor(s2, off, 64); }
  __shared__ float ss[4], ssq[4];
  int w = tid >> 6;
  if ((tid & 63) == 0) { ss[w] = s; ssq[w] = s2; }
  __syncthreads();
  s = ss[0] + ss[1] + ss[2] + ss[3];
  s2 = ssq[0] + ssq[1] + ssq[2] + ssq[3];
  float mean = s * (1.0f / 1024.0f);
  float var = (s2 - 1024.0f * mean * mean) * (1.0f / 1023.0f);
  var = fmaxf(var, 0.f);
  float inv = 1.0f / (sqrtf(var) + 1e-8f);
  float4 g4 = reinterpret_cast<const float4*>(gamma)[tid];
  float4 b4 = reinterpret_cast<const float4*>(beta)[tid];
  float4 r;
  r.x = g4.x * (x.x - mean) * inv + b4.x;
  r.y = g4.y * (x.y - mean) * inv + b4.y;
  r.z = g4.z * (x.z - mean) * inv + b4.z;
  r.w = g4.w * (x.w - mean) * inv + b4.w;
  o4[tid] = r;
}

extern "C" void kernel_launch(void* const* d_in, const int* in_sizes, int n_in,
                              void* d_out, int out_size, void* d_ws, size_t ws_size,
                              hipStream_t stream) {
  const float* queries = (const float*)d_in[0];
  const float* keys    = (const float*)d_in[1];
  const float* values  = (const float*)d_in[2];
  const float* Wq = (const float*)d_in[3];
  const float* bq = (const float*)d_in[4];
  const float* Wk = (const float*)d_in[5];
  const float* bk = (const float*)d_in[6];
  const float* Wv = (const float*)d_in[7];
  const float* bv = (const float*)d_in[8];
  const float* gamma = (const float*)d_in[9];
  const float* beta  = (const float*)d_in[10];
  float* out = (float*)d_out;

  char* ws = (char*)d_ws;
  const size_t SZ = (size_t)4096 * 1024 * 2;           // one bf16 [4096][1024] tensor (8 MB)
  bf16* Qb = (bf16*)(ws);
  bf16* Kb = (bf16*)(ws + SZ);
  bf16* Vt = (bf16*)(ws + 2 * SZ);                     // written directly by proj z==2
  bf16* Aq = (bf16*)(ws + 3 * SZ);
  bf16* Ak = (bf16*)(ws + 4 * SZ);
  bf16* Av = (bf16*)(ws + 5 * SZ);
  bf16* Wb = (bf16*)(ws + 6 * SZ);                     // 3 x [1024][1024] bf16 (6 MB)
  float* masks = (float*)(ws + 6 * SZ + 3 * 2097152);  // qmask[4096], kmaskAdd[4096]

  conv_kernel<<<15360, 128, 0, stream>>>(queries, keys, values, Wq, Wk, Wv, Aq, Ak, Av, Wb, masks);
  proj_kernel<<<dim3(32, 16, 3), 256, 0, stream>>>(Aq, Ak, Av, bq, bk, bv, Wb, Qb, Kb, Vt);
  flash_kernel<<<512, 512, 0, stream>>>(Qb, Kb, Vt, masks, out);
  ln_kernel<<<4096, 256, 0, stream>>>(out, queries, gamma, beta);
}

// Round 21
// 103.022 us; speedup vs baseline: 1.2542x; 1.0938x over previous
//
#include <hip/hip_runtime.h>
#include <hip/hip_bf16.h>

typedef __bf16 bf16;
typedef __bf16 bf16x8 __attribute__((ext_vector_type(8)));
typedef __bf16 bf16x4 __attribute__((ext_vector_type(4)));
typedef float f32x4 __attribute__((ext_vector_type(4)));
typedef unsigned int u32;

static constexpr int S = 2048, U = 1024, NB = 2, NH = 16, HD = 64;
static constexpr float NEGC = -4294967295.0f;
static constexpr float LOG2E = 1.44269504088896f;

__device__ __forceinline__ void gload_lds16(const void* g, void* l) {
  __builtin_amdgcn_global_load_lds((const __attribute__((address_space(1))) void*)g,
                                   (__attribute__((address_space(3))) void*)l, 16, 0, 0);
}

// single-instruction 2^x (raw v_exp_f32; args pre-scaled by log2e)
__device__ __forceinline__ float fexp2(float x) {
  float r;
  asm("v_exp_f32 %0, %1" : "=v"(r) : "v"(x));
  return r;
}

// ---------------- fused fp32->bf16 conversion (A + W) + padding masks ----------------
// masks[0..4095] = qmask (0/1); masks[4096..8191] = key additive mask (0 or NEGC)
__global__ __launch_bounds__(128) void conv_kernel(
    const float* __restrict__ queries, const float* __restrict__ keys, const float* __restrict__ values,
    const float* __restrict__ Wq, const float* __restrict__ Wk, const float* __restrict__ Wv,
    bf16* __restrict__ Aq, bf16* __restrict__ Ak, bf16* __restrict__ Av,
    bf16* __restrict__ Wb, float* __restrict__ masks)
{
  const int idx = blockIdx.x;               // 0..15359
  const int tid = threadIdx.x;
  const float* src;
  bf16* dst;
  if (idx < 4096)       { src = queries + (size_t)idx * U;          dst = Aq + (size_t)idx * U; }
  else if (idx < 8192)  { src = keys + (size_t)(idx - 4096) * U;    dst = Ak + (size_t)(idx - 4096) * U; }
  else if (idx < 12288) { src = values + (size_t)(idx - 8192) * U;  dst = Av + (size_t)(idx - 8192) * U; }
  else {
    int r2 = idx - 12288;
    int zz = r2 >> 10, row = r2 & 1023;
    src = (zz == 0 ? Wq : (zz == 1 ? Wk : Wv)) + (size_t)row * U;
    dst = Wb + ((size_t)zz << 20) + (size_t)row * U;
  }
  float4 f0 = *reinterpret_cast<const float4*>(src + tid * 8);
  float4 f1 = *reinterpret_cast<const float4*>(src + tid * 8 + 4);
  bf16x8 o;
  o[0]=(bf16)f0.x; o[1]=(bf16)f0.y; o[2]=(bf16)f0.z; o[3]=(bf16)f0.w;
  o[4]=(bf16)f1.x; o[5]=(bf16)f1.y; o[6]=(bf16)f1.z; o[7]=(bf16)f1.w;
  *reinterpret_cast<bf16x8*>(dst + tid * 8) = o;

  if (idx < 8192) {   // padding masks from row sums
    float s = f0.x + f0.y + f0.z + f0.w + f1.x + f1.y + f1.z + f1.w;
#pragma unroll
    for (int off = 1; off < 64; off <<= 1) s += __shfl_xor(s, off, 64);
    __shared__ float ss[2];
    if ((tid & 63) == 0) ss[tid >> 6] = s;
    __syncthreads();
    if (tid == 0) {
      bool nz = (ss[0] + ss[1]) != 0.0f;
      masks[idx] = (idx < 4096) ? (nz ? 1.0f : 0.0f)     // qmask multiplicative
                                : (nz ? 0.0f : NEGC);    // kmask additive
    }
  }
}

// ---------------- QKV projection (coalesced staging; z==2 writes Vt transposed) ----------------
// Q gets sc = 0.125*log2e: flash's softmax uses raw v_exp_f32 (2^x) directly.
__global__ __launch_bounds__(256) void proj_kernel(
    const bf16* __restrict__ Aq, const bf16* __restrict__ Ak, const bf16* __restrict__ Av,
    const float* __restrict__ bq, const float* __restrict__ bk, const float* __restrict__ bv,
    const bf16* __restrict__ Wb, bf16* __restrict__ Qb, bf16* __restrict__ Kb, bf16* __restrict__ Vt)
{
  const int z = blockIdx.z;
  const bf16* A     = z == 0 ? Aq : (z == 1 ? Ak : Av);
  const float* bias = z == 0 ? bq : (z == 1 ? bk : bv);
  bf16* O           = z == 0 ? Qb : Kb;       // z==2 goes through the Vt path
  const float sc    = z == 0 ? 0.125f * LOG2E : 1.0f;
  const bf16* W = Wb + ((size_t)z << 20);

  const int m0 = blockIdx.x * 128;
  const int n0 = blockIdx.y * 64;
  const int tid = threadIdx.x;
  const int lane = tid & 63;
  const int w = tid >> 6;
  const int lg = lane >> 4, li = lane & 15;
  const int wr = w >> 1, wc = w & 1;    // wave tile: 64 rows x 32 cols

  __shared__ bf16 As[2][128 * 64];   // [buf][row][chunk*8], 16 KB each
  __shared__ bf16 Ws[2][64 * 64];    // [buf][row][chunk*8],  8 KB each

  f32x4 acc[4][2] = {};

  auto stage = [&](int buf, int k0) {
#pragma unroll
    for (int j = 0; j < 4; ++j) {      // A: 4 VMEM instr/wave, 16 lines each
      int c = j * 256 + tid;
      int row = c >> 3, g = c & 7;
      gload_lds16(A + (size_t)(m0 + row) * U + k0 + ((g ^ (row & 7)) << 3),
                  (char*)As[buf] + (size_t)c * 16);
    }
#pragma unroll
    for (int j = 0; j < 2; ++j) {      // W: 2 VMEM instr/wave
      int c = j * 256 + tid;
      int row = c >> 3, g = c & 7;
      gload_lds16(W + (size_t)(n0 + row) * U + k0 + ((g ^ (row & 7)) << 3),
                  (char*)Ws[buf] + (size_t)c * 16);
    }
  };

  stage(0, 0);                         // 6 outstanding

  int cur = 0;
  for (int kt = 0; kt < 16; ++kt) {
    if (kt < 15) {
      stage(cur ^ 1, (kt + 1) * 64);   // +6 -> 12 outstanding
      asm volatile("s_waitcnt vmcnt(6)" ::: "memory");   // tile kt landed; next 6 stay in flight
    } else {
      asm volatile("s_waitcnt vmcnt(0)" ::: "memory");
    }
    __builtin_amdgcn_s_barrier();      // all waves' tile-kt DMA complete
    __builtin_amdgcn_sched_barrier(0); // no hoisting of ds_reads above the wait

    const bf16* AsC = As[cur];
    const bf16* WsC = Ws[cur];
    __builtin_amdgcn_s_setprio(1);
#pragma unroll
    for (int s = 0; s < 2; ++s) {
      const int gf = s * 4 + lg;
      const int gx = (gf ^ (li & 7)) << 3;   // swizzled chunk byte offset (row&7 == li&7)
      bf16x8 af[4], wf[2];
#pragma unroll
      for (int mi = 0; mi < 4; ++mi)
        af[mi] = *reinterpret_cast<const bf16x8*>(AsC + (size_t)(wr * 64 + mi * 16 + li) * 64 + gx);
#pragma unroll
      for (int ni = 0; ni < 2; ++ni)
        wf[ni] = *reinterpret_cast<const bf16x8*>(WsC + (size_t)(wc * 32 + ni * 16 + li) * 64 + gx);
#pragma unroll
      for (int mi = 0; mi < 4; ++mi)
#pragma unroll
        for (int ni = 0; ni < 2; ++ni)
          acc[mi][ni] = __builtin_amdgcn_mfma_f32_16x16x32_bf16(af[mi], wf[ni], acc[mi][ni], 0, 0, 0);
    }
    __builtin_amdgcn_s_setprio(0);
    __builtin_amdgcn_sched_barrier(0); // keep MFMA phase (and its ds_reads) before the barrier
    __builtin_amdgcn_s_barrier();      // all reads of cur done -> next iter may overwrite cur
    cur ^= 1;
  }

  // epilogue: bias+relu+scale -> swizzled LDS scratch -> coalesced stores
  // swizzle: stored_col = col ^ ((row&7)<<3) ^ (((row>>3)&7)<<3)  (transpose-read <=2-way)
  bf16* scr = (bf16*)As;               // 128 x 64 bf16 = 16 KB
#pragma unroll
  for (int ni = 0; ni < 2; ++ni) {
    int col = wc * 32 + ni * 16 + li;
    float bv_ = bias[n0 + col];
#pragma unroll
    for (int mi = 0; mi < 4; ++mi) {
#pragma unroll
      for (int r = 0; r < 4; ++r) {
        int row = wr * 64 + mi * 16 + lg * 4 + r;
        float v = acc[mi][ni][r] + bv_;
        v = (v > 0.f ? v : 0.f) * sc;
        scr[row * 64 + (col ^ ((row & 7) << 3) ^ (((row >> 3) & 7) << 3))] = (bf16)v;
      }
    }
  }
  __syncthreads();
  if (z != 2) {
    // row-major coalesced 16B stores to Q/K
    const int rbase = w * 32 + (lane >> 3);
    const int i = lane & 7;
#pragma unroll
    for (int p = 0; p < 4; ++p) {
      int rr = rbase + p * 8;
      bf16x8 v = *reinterpret_cast<const bf16x8*>(
          scr + rr * 64 + ((i ^ (rr & 7) ^ ((rr >> 3) & 7)) << 3));
      *reinterpret_cast<bf16x8*>(O + (size_t)(m0 + rr) * U + n0 + i * 8) = v;
    }
  } else {
    // fused V transpose: store Vt[hb][d][s] directly
    const int b2 = m0 >> 11;           // batch
    const int s0 = m0 & 2047;          // seq offset
    const int hb2 = blockIdx.y * 2 + b2;
    const int sc2 = tid & 15;          // s-chunk (8 s each)
#pragma unroll
    for (int p = 0; p < 4; ++p) {
      int d = p * 16 + (tid >> 4);
      bf16x8 v;
#pragma unroll
      for (int i = 0; i < 8; ++i)
        v[i] = scr[(sc2 * 8 + i) * 64 + (d ^ (i << 3) ^ ((sc2 & 7) << 3))];
      *reinterpret_cast<bf16x8*>(Vt + (size_t)(hb2 * 64 + d) * S + s0 + sc2 * 8) = v;
    }
  }
}

// ---------------- causal flash attention: swapped QK^T, in-lane softmax + defer-max, v_exp_f32 ----------------
__global__ __launch_bounds__(512) void flash_kernel(
    const bf16* __restrict__ Qb, const bf16* __restrict__ Kb, const bf16* __restrict__ Vt,
    const float* __restrict__ masks, float* __restrict__ Out)
{
  const int bid = blockIdx.x;          // grid 512
  const int hb = bid & 31;
  const int t = bid >> 5;              // 0..15
  const int qt2 = (t < 8) ? t : 23 - t;
  const int h = hb >> 1, b = hb & 1;
  const int q0 = qt2 * 128;
  const int nIter = 2 * qt2 + 2;
  const int tid = threadIdx.x;
  const int lane = tid & 63, w = tid >> 6;   // w 0..7
  const int lg = lane >> 4, li = lane & 15;
  const float* qmask = masks;
  const float* kmask = masks + 4096;   // additive: 0 or NEGC

  __shared__ bf16 Ks[2][8 * 64 * 8];   // [buf][g=d/8][k=64][8], 8 KB each
  __shared__ bf16 Vs[2][8 * 64 * 8];   // [buf][g2=k/8][d=64][8], 8 KB each
  __shared__ float Ms[2][64];          // [buf][k] additive key mask strip

  const int qq = q0 + w * 16 + li;     // this lane's q-row
  const bf16* qptr = Qb + (size_t)(b * S + qq) * U + h * 64;
  bf16x8 qf0 = *reinterpret_cast<const bf16x8*>(qptr + lg * 8);
  bf16x8 qf1 = *reinterpret_cast<const bf16x8*>(qptr + 32 + lg * 8);

  f32x4 oaccT[4] = {};                 // O^T frag: lane holds d = c2*16+lg*4+r for its q
  float m_run = -3.0e38f;
  float l_part = 0.0f;                 // per-lane PARTIAL row sum (combined once at end)

  const size_t krow_base = (size_t)b * S;
  const size_t vrow_base = (size_t)hb * 64;
  const int gK = tid >> 6, rK = tid & 63;

  auto stage = [&](int buf, int k0) {
    gload_lds16(Kb + (krow_base + k0 + rK) * U + h * 64 + gK * 8, (char*)Ks[buf] + (size_t)tid * 16);
    gload_lds16(Vt + (vrow_base + rK) * S + k0 + gK * 8,          (char*)Vs[buf] + (size_t)tid * 16);
  };

  // prologue: tile 0
  stage(0, 0);
  if (tid < 64) Ms[0][tid] = kmask[b * S + tid];
  __syncthreads();

  int cur = 0;
  for (int kv = 0; kv < nIter; ++kv) {
    const int k0 = kv * 64;
    float kaddn = 0.f;
    if (kv + 1 < nIter) {
      stage(cur ^ 1, k0 + 64);                         // prefetch hides under compute
      if (tid < 64) kaddn = kmask[b * S + k0 + 64 + tid];
    }

    const bf16* KsC = Ks[cur];
    const bf16* VsC = Vs[cur];

    // QK^T swapped: st[c] = S^T fragment (log2 scale: Q carries 0.125*log2e)
    f32x4 st[4] = {};
    __builtin_amdgcn_s_setprio(1);
#pragma unroll
    for (int s = 0; s < 2; ++s) {
      bf16x8 qf = s ? qf1 : qf0;
#pragma unroll
      for (int c = 0; c < 4; ++c) {
        bf16x8 kf = *reinterpret_cast<const bf16x8*>(KsC + (size_t)((s * 4 + lg) * 64 + c * 16 + li) * 8);
        st[c] = __builtin_amdgcn_mfma_f32_16x16x32_bf16(kf, qf, st[c], 0, 0, 0);
      }
    }
    __builtin_amdgcn_s_setprio(0);

    // masks: additive key mask (LDS strip, broadcast reads); causal only on last 2 tiles
    float p[4][4];
#pragma unroll
    for (int c = 0; c < 4; ++c) {
      f32x4 ka = *reinterpret_cast<const f32x4*>(&Ms[cur][c * 16 + lg * 4]);
#pragma unroll
      for (int r = 0; r < 4; ++r) p[c][r] = st[c][r] + ka[r];
    }
    if (kv >= 2 * qt2) {
#pragma unroll
      for (int c = 0; c < 4; ++c)
#pragma unroll
        for (int r = 0; r < 4; ++r)
          if (k0 + c * 16 + lg * 4 + r > qq) p[c][r] = NEGC;
    }

    // defer-max (T13): per-lane 16-value max; wave-uniform vote skips the
    // max-shuffles + m/alpha update + oacc rescale in the common case.
    // Threshold 8*log2e (log2 units).
    float mx = p[0][0];
#pragma unroll
    for (int c = 0; c < 4; ++c)
#pragma unroll
      for (int r = 0; r < 4; ++r) mx = fmaxf(mx, p[c][r]);
    if (!__all(mx <= m_run + 11.5416f)) {
      mx = fmaxf(mx, __shfl_xor(mx, 16, 64));
      mx = fmaxf(mx, __shfl_xor(mx, 32, 64));
      float mn = fmaxf(m_run, mx);
      float alpha = fexp2(m_run - mn);
      m_run = mn;
      l_part *= alpha;
#pragma unroll
      for (int c2 = 0; c2 < 4; ++c2)
#pragma unroll
        for (int r = 0; r < 4; ++r) oaccT[c2][r] *= alpha;
    }
    float ps = 0.f;
#pragma unroll
    for (int c = 0; c < 4; ++c)
#pragma unroll
      for (int r = 0; r < 4; ++r) {
        float pv = fexp2(p[c][r] - m_run);   // single v_exp_f32; bounded by e^8 on skip iters
        p[c][r] = pv;
        ps += pv;
      }
    l_part += ps;

    // pack P to bf16 pairs (u32) for register exchange
    u32 pk[4][2];
#pragma unroll
    for (int c = 0; c < 4; ++c) {
      union { bf16 hh[2]; u32 ww; } u0, u1;
      u0.hh[0] = (bf16)p[c][0]; u0.hh[1] = (bf16)p[c][1];
      u1.hh[0] = (bf16)p[c][2]; u1.hh[1] = (bf16)p[c][3];
      pk[c][0] = u0.ww; pk[c][1] = u1.ww;
    }

    // PV: O^T += V^T_frag x P^T_frag with permuted k-blocks.
    const bool lgEven = (lg & 1) == 0;
    __builtin_amdgcn_s_setprio(1);
#pragma unroll
    for (int s2 = 0; s2 < 2; ++s2) {
      u32 o0 = lgEven ? pk[(s2 << 1)][0]     : pk[(s2 << 1) | 1][0];
      u32 o1 = lgEven ? pk[(s2 << 1)][1]     : pk[(s2 << 1) | 1][1];
      u32 s0 = lgEven ? pk[(s2 << 1) | 1][0] : pk[(s2 << 1)][0];
      u32 s1 = lgEven ? pk[(s2 << 1) | 1][1] : pk[(s2 << 1)][1];
      u32 r0 = (u32)__shfl_xor((int)s0, 16, 64);
      u32 r1 = (u32)__shfl_xor((int)s1, 16, 64);
      union { u32 ww[4]; bf16x8 vv; } pt;
      pt.ww[0] = lgEven ? o0 : r0;
      pt.ww[1] = lgEven ? o1 : r1;
      pt.ww[2] = lgEven ? r0 : o0;
      pt.ww[3] = lgEven ? r1 : o1;
      const int g2v = s2 * 4 + (((lg & 1) << 1) | (lg >> 1));
#pragma unroll
      for (int c2 = 0; c2 < 4; ++c2) {
        bf16x8 vf = *reinterpret_cast<const bf16x8*>(VsC + (size_t)(g2v * 64 + c2 * 16 + li) * 8);
        oaccT[c2] = __builtin_amdgcn_mfma_f32_16x16x32_bf16(vf, pt.vv, oaccT[c2], 0, 0, 0);
      }
    }
    __builtin_amdgcn_s_setprio(0);

    if (kv + 1 < nIter && tid < 64) Ms[cur ^ 1][tid] = kaddn;
    __syncthreads();   // next-tile DMA complete + all reads of cur done
    cur ^= 1;
  }

  // epilogue: combine partial l across the 4 owning lanes (deferred from per-iter),
  // normalize, query-mask, scattered O^T store (L2 write-back merges)
  float l_run = l_part;
  l_run += __shfl_xor(l_run, 16, 64);
  l_run += __shfl_xor(l_run, 32, 64);
  float qm = qmask[b * S + qq];
  float sc = qm / l_run;
  float* orow = Out + (size_t)(b * S + qq) * U + h * 64;
#pragma unroll
  for (int c2 = 0; c2 < 4; ++c2)
#pragma unroll
    for (int r = 0; r < 4; ++r)
      orow[c2 * 16 + lg * 4 + r] = oaccT[c2][r] * sc;
}

// ---------------- residual + LayerNorm (ddof=1), in-place on d_out, float4 ----------------
__global__ __launch_bounds__(256) void ln_kernel(float* __restrict__ out, const float* __restrict__ queries,
                                                 const float* __restrict__ gamma, const float* __restrict__ beta)
{
  int row = blockIdx.x;
  const float4* q4 = reinterpret_cast<const float4*>(queries + (size_t)row * U);
  float4* o4 = reinterpret_cast<float4*>(out + (size_t)row * U);
  int tid = threadIdx.x;
  float4 ov = o4[tid], qv = q4[tid];
  float4 x;
  x.x = ov.x + qv.x; x.y = ov.y + qv.y; x.z = ov.z + qv.z; x.w = ov.w + qv.w;
  float s  = x.x + x.y + x.z + x.w;
  float s2 = x.x * x.x + x.y * x.y + x.z * x.z + x.w * x.w;
#pragma unroll
  for (int off = 1; off < 64; off <<= 1) { s += __shfl_xor(s, off, 64); s2 += __shfl_xor(s2, off, 64); }
  __shared__ float ss[4], ssq[4];
  int w = tid >> 6;
  if ((tid & 63) == 0) { ss[w] = s; ssq[w] = s2; }
  __syncthreads();
  s = ss[0] + ss[1] + ss[2] + ss[3];
  s2 = ssq[0] + ssq[1] + ssq[2] + ssq[3];
  float mean = s * (1.0f / 1024.0f);
  float var = (s2 - 1024.0f * mean * mean) * (1.0f / 1023.0f);
  var = fmaxf(var, 0.f);
  float inv = 1.0f / (sqrtf(var) + 1e-8f);
  float4 g4 = reinterpret_cast<const float4*>(gamma)[tid];
  float4 b4 = reinterpret_cast<const float4*>(beta)[tid];
  float4 r;
  r.x = g4.x * (x.x - mean) * inv + b4.x;
  r.y = g4.y * (x.y - mean) * inv + b4.y;
  r.z = g4.z * (x.z - mean) * inv + b4.z;
  r.w = g4.w * (x.w - mean) * inv + b4.w;
  o4[tid] = r;
}

extern "C" void kernel_launch(void* const* d_in, const int* in_sizes, int n_in,
                              void* d_out, int out_size, void* d_ws, size_t ws_size,
                              hipStream_t stream) {
  const float* queries = (const float*)d_in[0];
  const float* keys    = (const float*)d_in[1];
  const float* values  = (const float*)d_in[2];
  const float* Wq = (const float*)d_in[3];
  const float* bq = (const float*)d_in[4];
  const float* Wk = (const float*)d_in[5];
  const float* bk = (const float*)d_in[6];
  const float* Wv = (const float*)d_in[7];
  const float* bv = (const float*)d_in[8];
  const float* gamma = (const float*)d_in[9];
  const float* beta  = (const float*)d_in[10];
  float* out = (float*)d_out;

  char* ws = (char*)d_ws;
  const size_t SZ = (size_t)4096 * 1024 * 2;           // one bf16 [4096][1024] tensor (8 MB)
  bf16* Qb = (bf16*)(ws);
  bf16* Kb = (bf16*)(ws + SZ);
  bf16* Vt = (bf16*)(ws + 2 * SZ);                     // written directly by proj z==2
  bf16* Aq = (bf16*)(ws + 3 * SZ);
  bf16* Ak = (bf16*)(ws + 4 * SZ);
  bf16* Av = (bf16*)(ws + 5 * SZ);
  bf16* Wb = (bf16*)(ws + 6 * SZ);                     // 3 x [1024][1024] bf16 (6 MB)
  float* masks = (float*)(ws + 6 * SZ + 3 * 2097152);  // qmask[4096], kmaskAdd[4096]

  conv_kernel<<<15360, 128, 0, stream>>>(queries, keys, values, Wq, Wk, Wv, Aq, Ak, Av, Wb, masks);
  proj_kernel<<<dim3(32, 16, 3), 256, 0, stream>>>(Aq, Ak, Av, bq, bk, bv, Wb, Qb, Kb, Vt);
  flash_kernel<<<512, 512, 0, stream>>>(Qb, Kb, Vt, masks, out);
  ln_kernel<<<4096, 256, 0, stream>>>(out, queries, gamma, beta);
}